// Round 1
// baseline (191.814 us; speedup 1.0000x reference)
//
#include <hip/hip_runtime.h>

#define MDIM 512
#define LCH 31
#define CDIM 542   // MD + L - 1
#define INW 1024

// ws layout (floats):
//  XM_OFF   : Xm [m][i][n]   512*31*512 = 8126464
//  YN_OFF   : yn_raw [m][c]  512*542    = 277504
//  PMY_OFF  : per-row maxes for yn      = 512
//  PMT_OFF  : per-block maxes for t     = 31744
//  SCL_OFF  : invMy, invMt              = 2
#define XM_OFF  0
#define YN_OFF  (XM_OFF + MDIM*LCH*MDIM)
#define PMY_OFF (YN_OFF + MDIM*CDIM)
#define PMT_OFF (PMY_OFF + MDIM)
#define NB3     31744                 // 512*512*31 / 256
#define SCL_OFF (PMT_OFF + NB3)

__device__ __forceinline__ void resize_wts(int j, float w[4], int idx[4]) {
    const float base[4] = {0.125f, 0.375f, 0.375f, 0.125f};
    float s = 0.f;
    #pragma unroll
    for (int a = 0; a < 4; ++a) {
        int i = 2*j - 1 + a;
        bool ok = (i >= 0) && (i < INW);
        idx[a] = ok ? i : 0;
        w[a] = ok ? base[a] : 0.f;
        s += w[a];
    }
    float inv = 1.0f / s;
    #pragma unroll
    for (int a = 0; a < 4; ++a) w[a] *= inv;
}

// K1: bilinear resize (4x4 taps) + spectral conv along L + H multiply.
// One thread per (m,n). Writes Xm[m][l][n] (transposed so K2 is coalesced).
__global__ void k1_resize_conv(const float* __restrict__ X,
                               const float* __restrict__ H,
                               float* __restrict__ Xm) {
    int tid = blockIdx.x * blockDim.x + threadIdx.x;
    int n = tid & (MDIM - 1);
    int m = tid >> 9;

    float wy[4], wx[4];
    int   iy[4], ix[4];
    resize_wts(m, wy, iy);
    resize_wts(n, wx, ix);

    float xr[LCH];
    #pragma unroll
    for (int l = 0; l < LCH; ++l) xr[l] = 0.f;

    #pragma unroll
    for (int a = 0; a < 4; ++a) {
        #pragma unroll
        for (int b = 0; b < 4; ++b) {
            float w = wy[a] * wx[b];
            if (w == 0.f) continue;
            const float* p = X + ((size_t)iy[a] * INW + ix[b]) * LCH;
            #pragma unroll
            for (int l = 0; l < LCH; ++l) xr[l] = fmaf(w, p[l], xr[l]);
        }
    }

    const float* h = H + (size_t)(m * MDIM + n) * LCH;
    #pragma unroll
    for (int l = 0; l < LCH; ++l) {
        float c = 0.5f * xr[l];
        if (l > 0)       c += 0.25f * xr[l-1];
        if (l < LCH - 1) c += 0.25f * xr[l+1];
        Xm[((size_t)m * LCH + l) * MDIM + n] = c * h[l];
    }
}

// K2: yn[m,c] = sum_i Xm[m][i][c-i] (valid i); per-row (block) max.
__global__ void k2_shiftsum(const float* __restrict__ Xm,
                            float* __restrict__ yn,
                            float* __restrict__ pmax) {
    int m = blockIdx.x;
    float lmax = -3.4e38f;
    for (int c = threadIdx.x; c < CDIM; c += blockDim.x) {
        float s = 0.f;
        int ilo = max(0, c - (MDIM - 1));
        int ihi = min(LCH - 1, c);
        for (int i = ilo; i <= ihi; ++i)
            s += Xm[((size_t)m * LCH + i) * MDIM + (c - i)];
        yn[m * CDIM + c] = s;
        lmax = fmaxf(lmax, s);
    }
    __shared__ float red[256];
    red[threadIdx.x] = lmax;
    __syncthreads();
    for (int s = 128; s > 0; s >>= 1) {
        if ((int)threadIdx.x < s)
            red[threadIdx.x] = fmaxf(red[threadIdx.x], red[threadIdx.x + s]);
        __syncthreads();
    }
    if (threadIdx.x == 0) pmax[m] = red[0];
}

// Reduce n partial maxes -> out_inv[0] = 1/max
__global__ void kmax_reduce(const float* __restrict__ pmax, int n,
                            float* __restrict__ out_inv) {
    __shared__ float red[256];
    float lmax = -3.4e38f;
    for (int i = threadIdx.x; i < n; i += 256)
        lmax = fmaxf(lmax, pmax[i]);
    red[threadIdx.x] = lmax;
    __syncthreads();
    for (int s = 128; s > 0; s >>= 1) {
        if ((int)threadIdx.x < s)
            red[threadIdx.x] = fmaxf(red[threadIdx.x], red[threadIdx.x + s]);
        __syncthreads();
    }
    if (threadIdx.x == 0) out_inv[0] = 1.0f / red[0];
}

// K3: per element (m,n,i): r[c]=yn[m][c]*invMy - y[m][c], c=n+i;
// t = H * (0.25 r[c-1] + 0.5 r[c] + 0.25 r[c+1])  (i-boundary clipped);
// write t to out, track per-block max.
__global__ void k3_grad(const float* __restrict__ yn,
                        const float* __restrict__ y,
                        const float* __restrict__ H,
                        const float* __restrict__ scl,
                        float* __restrict__ out,
                        float* __restrict__ pmax) {
    int tid = blockIdx.x * blockDim.x + threadIdx.x;
    int i = tid % LCH;
    int rest = tid / LCH;
    int n = rest & (MDIM - 1);
    int m = rest >> 9;
    float inv = scl[0];
    int c = n + i;
    const float* ynr = yn + (size_t)m * CDIM;
    const float* yr  = y  + (size_t)m * CDIM;

    float v = 0.5f * (ynr[c] * inv - yr[c]);
    if (i > 0)       v += 0.25f * (ynr[c-1] * inv - yr[c-1]);
    if (i < LCH - 1) v += 0.25f * (ynr[c+1] * inv - yr[c+1]);
    float t = H[tid] * v;
    out[tid] = t;

    __shared__ float red[256];
    red[threadIdx.x] = t;
    __syncthreads();
    for (int s = 128; s > 0; s >>= 1) {
        if ((int)threadIdx.x < s)
            red[threadIdx.x] = fmaxf(red[threadIdx.x], red[threadIdx.x + s]);
        __syncthreads();
    }
    if (threadIdx.x == 0) pmax[blockIdx.x] = red[0];
}

// K4: scale output by 1/max
__global__ void k4_scale(float* __restrict__ out, const float* __restrict__ scl) {
    int tid = blockIdx.x * blockDim.x + threadIdx.x;
    out[tid] *= scl[0];
}

extern "C" void kernel_launch(void* const* d_in, const int* in_sizes, int n_in,
                              void* d_out, int out_size, void* d_ws, size_t ws_size,
                              hipStream_t stream) {
    const float* X = (const float*)d_in[0];
    const float* y = (const float*)d_in[1];
    const float* H = (const float*)d_in[2];
    float* out = (float*)d_out;
    float* ws  = (float*)d_ws;

    float* Xm    = ws + XM_OFF;
    float* yn    = ws + YN_OFF;
    float* pmaxY = ws + PMY_OFF;
    float* pmaxT = ws + PMT_OFF;
    float* scl   = ws + SCL_OFF;   // [0]=invMy, [1]=invMt

    // K1: 512*512 threads
    k1_resize_conv<<<(MDIM*MDIM)/256, 256, 0, stream>>>(X, H, Xm);
    // K2: one block per row m
    k2_shiftsum<<<MDIM, 256, 0, stream>>>(Xm, yn, pmaxY);
    kmax_reduce<<<1, 256, 0, stream>>>(pmaxY, MDIM, scl);
    // K3: 512*512*31 threads = 31744 blocks
    k3_grad<<<NB3, 256, 0, stream>>>(yn, y, H, scl, out, pmaxT);
    kmax_reduce<<<1, 256, 0, stream>>>(pmaxT, NB3, scl + 1);
    k4_scale<<<NB3, 256, 0, stream>>>(out, scl + 1);
}